// Round 5
// baseline (135.430 us; speedup 1.0000x reference)
//
#include <hip/hip_runtime.h>
#include <stdint.h>

// ConvMemory v6 (fused, latency-tolerant):
// out = (3x3 conv of E=exp(x), W=memory) / (3x3 boxsum of chan-sum(E))
// Zero-padding before softmax => OOB taps contribute exp(0)=1 to num & denom.
// convf: 4x16 tile, 256 thr (4 waves), 2048 blocks (XCD-chunked: 1 batch image
// per XCD). Staging: granule-thread groups of 8 lanes load 8ch x (4|1) px of x,
// exp+pack bf16 in-register, write conflict-free b128 LDS (slot = g ^ (p&7));
// per-pixel channel-sum S via 8-lane __shfl_xor reduce (no atomics, no extra
// barrier). ONE __syncthreads. Then verified 36-chunk MFMA K-loop
// (mfma_f32_32x32x16_bf16, A=W from L2, B=E from LDS, 4-deep prefetch),
// epilogue with inlined 3x3 boxsum Zinv.

#define Cn 64
#define Hn 128
#define Wn 128
#define OC 128
#define HW (Hn * Wn)

typedef __attribute__((ext_vector_type(8))) short bf16x8_t;
typedef __attribute__((ext_vector_type(16))) float f32x16_t;

__device__ inline unsigned short f2bf(float f) {
    union { float f; uint32_t u; } v; v.f = f;
    uint32_t u = v.u;
    u += 0x7fffu + ((u >> 16) & 1u);
    return (unsigned short)(u >> 16);
}
__device__ inline float bf_lo(uint32_t u) {
    union { uint32_t u; float f; } v; v.u = u << 16;
    return v.f;
}
__device__ inline float bf_hi(uint32_t u) {
    union { uint32_t u; float f; } v; v.u = u & 0xffff0000u;
    return v.f;
}

// ---------------------------------------------------------------------------
// prep: memory[576][128] f32 -> Bt2 bf16 chunks: chunk cid=(kc*2+hi), 128 n's,
// 16B per n = 8 sequential channels c = (kc&3)*16 + hi*8 + j, q = kc>>2 (kh*3+kw).
// ---------------------------------------------------------------------------
__global__ void prep_b2(const float* __restrict__ mem, uint4* __restrict__ Bt2) {
    int u = blockIdx.x * 256 + threadIdx.x;   // 0..9215
    int n = u & 127;
    int cid = u >> 7;                         // 0..71
    int hi = cid & 1;
    int kc = cid >> 1;                        // 0..35
    int q = kc >> 2, cblk = kc & 3;
    unsigned short h8[8];
#pragma unroll
    for (int j = 0; j < 8; j++) {
        int c = cblk * 16 + hi * 8 + j;
        h8[j] = f2bf(mem[(c * 9 + q) * OC + n]);
    }
    Bt2[cid * 128 + n] = *(const uint4*)h8;
}

// ---------------------------------------------------------------------------
__global__ __launch_bounds__(256, 4) void convf(const float* __restrict__ x,
                                                const uint4* __restrict__ Bt2,
                                                float* __restrict__ out) {
    __shared__ __align__(16) uint4 EtL[108 * 8];   // 13824 B, [p][slot], 6x18 halo
    __shared__ float Sh[108];

    int bid0 = blockIdx.x;
    int bid = ((bid0 & 7) << 8) | (bid0 >> 3);   // XCD chunk: XCD i -> batch i
    int b = bid >> 8;                            // 2048 = 8 b * 32 ty * 8 tx
    int ty = (bid >> 3) & 31, tx = bid & 7;
    int h0 = ty * 4, w0 = tx * 16;
    int t = threadIdx.x;
    int lane = t & 63;

    const float* xb = x + (size_t)b * Cn * HW;

    // ---- staging: 288 items = pg(36 = py6 x qs6) x g(8); lane group of 8 = one
    //      pixel-group, granule g = channels 8g..8g+7 (pair-packed bf16 words).
#pragma unroll
    for (int it = 0; it < 2; it++) {
        int u = it * 256 + t;
        if (u < 288) {
            int g = u & 7;
            int pg = u >> 3;                  // 0..35
            int py = pg / 6, qs = pg % 6;
            int gy = h0 - 1 + py;
            bool inrow = (gy >= 0) & (gy < Hn);

            if (qs >= 1 && qs <= 4) {         // core: 4 px, halo px = (qs-1)*4+1 ..
                int px0 = (qs - 1) * 4 + 1;
                float4 v[8];
                if (inrow) {
                    const float* basep = xb + (size_t)(8 * g) * HW
                                       + (size_t)gy * Wn + (w0 + (qs - 1) * 4);
#pragma unroll
                    for (int k = 0; k < 8; k++)
                        v[k] = *(const float4*)(basep + (size_t)k * HW);
                }
                float s4[4];
#pragma unroll
                for (int i = 0; i < 4; i++) {
                    uint32_t wd[4];
                    float si;
                    if (inrow) {
                        si = 0.f;
#pragma unroll
                        for (int j = 0; j < 4; j++) {
                            float a = ((const float*)&v[2 * j])[i];
                            float c = ((const float*)&v[2 * j + 1])[i];
                            uint32_t pk = (uint32_t)f2bf(__expf(a))
                                        | ((uint32_t)f2bf(__expf(c)) << 16);
                            wd[j] = pk;
                            si += bf_lo(pk) + bf_hi(pk);
                        }
                    } else {
                        wd[0] = wd[1] = wd[2] = wd[3] = 0x3F803F80u;
                        si = 8.f;
                    }
                    int p = py * 18 + px0 + i;
                    EtL[p * 8 + (g ^ (p & 7))] = *(const uint4*)wd;
                    s4[i] = si;
                }
                // 8-lane granule reduce -> 64-channel sums for the 4 px
#pragma unroll
                for (int m = 1; m < 8; m <<= 1) {
#pragma unroll
                    for (int i = 0; i < 4; i++)
                        s4[i] += __shfl_xor(s4[i], m);
                }
                if (g < 4) Sh[py * 18 + px0 + g] = s4[g];
            } else {                          // edge: 1 px, halo px 0 or 17
                int side = (qs == 5);
                int p = py * 18 + (side ? 17 : 0);
                int gxe = side ? (w0 + 16) : (w0 - 1);
                bool real = inrow && (gxe >= 0) && (gxe < Wn);
                uint32_t wd[4];
                float s;
                if (real) {
                    const float* basep = xb + (size_t)(8 * g) * HW
                                       + (size_t)gy * Wn + gxe;
                    s = 0.f;
#pragma unroll
                    for (int j = 0; j < 4; j++) {
                        float a = basep[(size_t)(2 * j) * HW];
                        float c = basep[(size_t)(2 * j + 1) * HW];
                        uint32_t pk = (uint32_t)f2bf(__expf(a))
                                    | ((uint32_t)f2bf(__expf(c)) << 16);
                        wd[j] = pk;
                        s += bf_lo(pk) + bf_hi(pk);
                    }
                } else {
                    wd[0] = wd[1] = wd[2] = wd[3] = 0x3F803F80u;
                    s = 8.f;
                }
                EtL[p * 8 + (g ^ (p & 7))] = *(const uint4*)wd;
#pragma unroll
                for (int m = 1; m < 8; m <<= 1)
                    s += __shfl_xor(s, m);
                if (g == 0) Sh[p] = s;
            }
        }
    }
    __syncthreads();

    // ---- MFMA K-loop: wave wo = oc 32-block; all waves share the 64-px tile ----
    int wo = t >> 6;                  // 0..3
    int l31 = lane & 31, hi = lane >> 5;
    int x0v = l31 & 15;
    int y0[2];
    y0[0] = 0 + (l31 >> 4);
    y0[1] = 2 + (l31 >> 4);

    f32x16_t acc[2];
#pragma unroll
    for (int j = 0; j < 2; j++)
#pragma unroll
        for (int r = 0; r < 16; r++) acc[j][r] = 0.f;

    bf16x8_t Wf[4], Ef[4][2];

    auto loadW = [&](int kc, int s) {
        Wf[s] = *(const bf16x8_t*)(Bt2 + (size_t)((kc * 2 + hi) * 128 + wo * 32 + l31));
    };
    auto loadE = [&](int kc, int s) {
        int q = kc >> 2, cblk = kc & 3;
        int kh = q / 3, kw = q - kh * 3;
        int ge = cblk * 2 + hi;
#pragma unroll
        for (int j = 0; j < 2; j++) {
            int pix = (y0[j] + kh) * 18 + (x0v + kw);
            Ef[s][j] = *(const bf16x8_t*)&EtL[pix * 8 + (ge ^ (pix & 7))];
        }
    };

    loadW(0, 0); loadE(0, 0);
    loadW(1, 1); loadE(1, 1);
    loadW(2, 2); loadE(2, 2);
    loadW(3, 3); loadE(3, 3);
#pragma unroll
    for (int kc = 0; kc < 36; kc++) {
        int s = kc & 3;
#pragma unroll
        for (int j = 0; j < 2; j++)
            acc[j] = __builtin_amdgcn_mfma_f32_32x32x16_bf16(
                Wf[s], Ef[s][j], acc[j], 0, 0, 0);
        if (kc + 4 < 36) { loadW(kc + 4, s); loadE(kc + 4, s); }
    }

    // ---- epilogue: inline Zinv (3x3 boxsum of Sh), then scaled stores ----
#pragma unroll
    for (int j = 0; j < 2; j++) {
        float z = 0.f;
#pragma unroll
        for (int dy = 0; dy < 3; dy++)
#pragma unroll
            for (int dx = 0; dx < 3; dx++)
                z += Sh[(y0[j] + dy) * 18 + (x0v + dx)];
        float zi = 1.0f / z;
        float* ob = out + (size_t)b * OC * HW + (size_t)(wo * 32 + 4 * hi) * HW
                  + (h0 + y0[j]) * Wn + (w0 + x0v);
#pragma unroll
        for (int r = 0; r < 16; r++) {
            int nrel = (r & 3) + 8 * (r >> 2);   // + 4*hi folded into ob
            ob[(size_t)nrel * HW] = acc[j][r] * zi;
        }
    }
}

// ---------------------------------------------------------------------------
extern "C" void kernel_launch(void* const* d_in, const int* in_sizes, int n_in,
                              void* d_out, int out_size, void* d_ws, size_t ws_size,
                              hipStream_t stream) {
    const float* x = (const float*)d_in[0];
    const float* mem = (const float*)d_in[1];
    float* out = (float*)d_out;

    uint4* Bt2 = (uint4*)d_ws;                 // 147,456 B

    prep_b2<<<36, 256, 0, stream>>>(mem, Bt2);
    convf<<<2048, 256, 0, stream>>>(x, Bt2, out);
}

// Round 6
// 120.054 us; speedup vs baseline: 1.1281x; 1.1281x over previous
//
#include <hip/hip_runtime.h>
#include <stdint.h>

// ConvMemory v7: out = (3x3 conv of E=exp(x), W=memory) / (3x3 boxsum of chan-sum(E))
// Zero-padding before softmax => OOB taps contribute exp(0)=1 to num & denom.
// Fused convf, 8x16 tile, 512 thr (8 waves), 1024 blocks (XCD-chunk swizzled).
// Fixes vs v3 (45.8us): W prefetch ring depth 6 issued at KERNEL ENTRY (covers
// ~200cyc L2 latency; v3's depth-3 stalled every iter), ONE barrier (S via
// 8-lane __shfl_xor during staging, Zinv inlined in epilogue), setprio around
// MFMA. Staging: lane-adjacent granule groups (g = t&7), conflict-free b128
// LDS writes slot = g ^ (p&7); K-loop reads match.

#define Cn 64
#define Hn 128
#define Wn 128
#define OC 128
#define HW (Hn * Wn)

typedef __attribute__((ext_vector_type(8))) short bf16x8_t;
typedef __attribute__((ext_vector_type(16))) float f32x16_t;

__device__ inline unsigned short f2bf(float f) {
    union { float f; uint32_t u; } v; v.f = f;
    uint32_t u = v.u;
    u += 0x7fffu + ((u >> 16) & 1u);
    return (unsigned short)(u >> 16);
}
__device__ inline float bf_lo(uint32_t u) {
    union { uint32_t u; float f; } v; v.u = u << 16;
    return v.f;
}
__device__ inline float bf_hi(uint32_t u) {
    union { uint32_t u; float f; } v; v.u = u & 0xffff0000u;
    return v.f;
}

// ---------------------------------------------------------------------------
// prep: memory[576][128] f32 -> Bt2 bf16 chunks: chunk cid=(kc*2+hi), 128 n's,
// 16B per n = 8 channels c = (kc&3)*16 + hi*8 + j, q = kc>>2 (kh*3+kw).
// ---------------------------------------------------------------------------
__global__ void prep_b2(const float* __restrict__ mem, uint4* __restrict__ Bt2) {
    int u = blockIdx.x * 256 + threadIdx.x;   // 0..9215
    int n = u & 127;
    int cid = u >> 7;                         // 0..71
    int hi = cid & 1;
    int kc = cid >> 1;                        // 0..35
    int q = kc >> 2, cblk = kc & 3;
    unsigned short h8[8];
#pragma unroll
    for (int j = 0; j < 8; j++) {
        int c = cblk * 16 + hi * 8 + j;
        h8[j] = f2bf(mem[(c * 9 + q) * OC + n]);
    }
    Bt2[cid * 128 + n] = *(const uint4*)h8;
}

// ---------------------------------------------------------------------------
__global__ __launch_bounds__(512, 4) void convf(const float* __restrict__ x,
                                                const uint4* __restrict__ Bt2,
                                                float* __restrict__ out) {
    __shared__ __align__(16) uint4 EtL[180 * 8];   // 23040 B, [p][slot], 10x18 halo
    __shared__ float Sh[180];

    int bid0 = blockIdx.x;
    int bid = ((bid0 & 7) << 7) | (bid0 >> 3);   // XCD chunk swizzle, 1024 = 8*128
    int b = bid >> 7;                            // 8 b * 16 ty * 8 tx
    int ty = (bid >> 3) & 15, tx = bid & 7;
    int h0 = ty * 8, w0 = tx * 16;
    int t = threadIdx.x;
    int lane = t & 63, wid = t >> 6;

    // ---- K-loop geometry (needed now: W prefetch starts before staging) ----
    int wo = wid & 3;                 // oc 32-block
    int wp = wid >> 2;                // px-pair 0..1
    int l31 = lane & 31, hi = lane >> 5;
    int x0v = l31 & 15;
    int y0[2];
    y0[0] = (wp * 2 + 0) * 2 + (l31 >> 4);
    y0[1] = (wp * 2 + 1) * 2 + (l31 >> 4);

    bf16x8_t Wf[6], Ef[3][2];
    auto loadW = [&](int kc, int s) {
        Wf[s] = *(const bf16x8_t*)(Bt2 + (size_t)((kc * 2 + hi) * 128 + wo * 32 + l31));
    };
    // issue 6 W loads immediately — they complete while staging runs
    loadW(0, 0); loadW(1, 1); loadW(2, 2);
    loadW(3, 3); loadW(4, 4); loadW(5, 5);

    const float* xb = x + (size_t)b * Cn * HW;

    // ---- staging: 480 items = pg(60 = py10 x qs6) x g(8), g = t&7 so the 8
    //      granule-threads of one pixel-group are lane-adjacent (shfl reduce).
    if (t < 480) {
        int g = t & 7;                    // granule = channels 8g..8g+7
        int pg = t >> 3;                  // 0..59
        int py = pg / 6, qs = pg % 6;
        int gy = h0 - 1 + py;
        bool inrow = (gy >= 0) & (gy < Hn);

        if (qs >= 1 && qs <= 4) {         // core: 4 px, halo px = (qs-1)*4+1 ..
            int px0 = (qs - 1) * 4 + 1;
            float4 v[8];
            if (inrow) {
                const float* basep = xb + (size_t)(8 * g) * HW
                                   + (size_t)gy * Wn + (w0 + (qs - 1) * 4);
#pragma unroll
                for (int k = 0; k < 8; k++)
                    v[k] = *(const float4*)(basep + (size_t)k * HW);
            }
            float s4[4];
#pragma unroll
            for (int i = 0; i < 4; i++) {
                uint32_t wd[4];
                float si;
                if (inrow) {
                    si = 0.f;
#pragma unroll
                    for (int j = 0; j < 4; j++) {
                        float a = ((const float*)&v[2 * j])[i];
                        float c = ((const float*)&v[2 * j + 1])[i];
                        uint32_t pk = (uint32_t)f2bf(__expf(a))
                                    | ((uint32_t)f2bf(__expf(c)) << 16);
                        wd[j] = pk;
                        si += bf_lo(pk) + bf_hi(pk);
                    }
                } else {
                    wd[0] = wd[1] = wd[2] = wd[3] = 0x3F803F80u;
                    si = 8.f;
                }
                int p = py * 18 + px0 + i;
                EtL[p * 8 + (g ^ (p & 7))] = *(const uint4*)wd;
                s4[i] = si;
            }
            // 8-lane granule reduce -> 64-channel sums for the 4 px
#pragma unroll
            for (int m = 1; m < 8; m <<= 1) {
#pragma unroll
                for (int i = 0; i < 4; i++)
                    s4[i] += __shfl_xor(s4[i], m);
            }
            if (g < 4) Sh[py * 18 + px0 + g] = s4[g];
        } else {                          // edge: 1 px, halo px 0 or 17
            int side = (qs == 5);
            int p = py * 18 + (side ? 17 : 0);
            int gxe = side ? (w0 + 16) : (w0 - 1);
            bool real = inrow && (gxe >= 0) && (gxe < Wn);
            uint32_t wd[4];
            float s;
            if (real) {
                const float* basep = xb + (size_t)(8 * g) * HW
                                   + (size_t)gy * Wn + gxe;
                s = 0.f;
#pragma unroll
                for (int j = 0; j < 4; j++) {
                    float a = basep[(size_t)(2 * j) * HW];
                    float c = basep[(size_t)(2 * j + 1) * HW];
                    uint32_t pk = (uint32_t)f2bf(__expf(a))
                                | ((uint32_t)f2bf(__expf(c)) << 16);
                    wd[j] = pk;
                    s += bf_lo(pk) + bf_hi(pk);
                }
            } else {
                wd[0] = wd[1] = wd[2] = wd[3] = 0x3F803F80u;
                s = 8.f;
            }
            EtL[p * 8 + (g ^ (p & 7))] = *(const uint4*)wd;
#pragma unroll
            for (int m = 1; m < 8; m <<= 1)
                s += __shfl_xor(s, m);
            if (g == 0) Sh[p] = s;
        }
    }
    __syncthreads();

    // ---- MFMA K-loop: W ring depth 6 (global/L2), E ring depth 3 (LDS) ----
    f32x16_t acc[2];
#pragma unroll
    for (int j = 0; j < 2; j++)
#pragma unroll
        for (int r = 0; r < 16; r++) acc[j][r] = 0.f;

    auto loadE = [&](int kc, int s) {
        int q = kc >> 2, cblk = kc & 3;
        int kh = q / 3, kw = q - kh * 3;
        int ge = cblk * 2 + hi;
#pragma unroll
        for (int j = 0; j < 2; j++) {
            int pix = (y0[j] + kh) * 18 + (x0v + kw);
            Ef[s][j] = *(const bf16x8_t*)&EtL[pix * 8 + (ge ^ (pix & 7))];
        }
    };

    loadE(0, 0); loadE(1, 1); loadE(2, 2);
#pragma unroll
    for (int kc = 0; kc < 36; kc++) {
        int sE = kc % 3, sW = kc % 6;
        __builtin_amdgcn_s_setprio(1);
#pragma unroll
        for (int j = 0; j < 2; j++)
            acc[j] = __builtin_amdgcn_mfma_f32_32x32x16_bf16(
                Wf[sW], Ef[sE][j], acc[j], 0, 0, 0);
        __builtin_amdgcn_s_setprio(0);
        if (kc + 3 < 36) loadE(kc + 3, sE);
        if (kc + 6 < 36) loadW(kc + 6, sW);
    }

    // ---- epilogue: inline Zinv (3x3 boxsum of Sh), then scaled stores ----
#pragma unroll
    for (int j = 0; j < 2; j++) {
        float z = 0.f;
#pragma unroll
        for (int dy = 0; dy < 3; dy++)
#pragma unroll
            for (int dx = 0; dx < 3; dx++)
                z += Sh[(y0[j] + dy) * 18 + (x0v + dx)];
        float zi = 1.0f / z;
        float* ob = out + (size_t)b * OC * HW + (size_t)(wo * 32 + 4 * hi) * HW
                  + (h0 + y0[j]) * Wn + (w0 + x0v);
#pragma unroll
        for (int r = 0; r < 16; r++) {
            int nrel = (r & 3) + 8 * (r >> 2);   // + 4*hi folded into ob
            ob[(size_t)nrel * HW] = acc[j][r] * zi;
        }
    }
}

// ---------------------------------------------------------------------------
extern "C" void kernel_launch(void* const* d_in, const int* in_sizes, int n_in,
                              void* d_out, int out_size, void* d_ws, size_t ws_size,
                              hipStream_t stream) {
    const float* x = (const float*)d_in[0];
    const float* mem = (const float*)d_in[1];
    float* out = (float*)d_out;

    uint4* Bt2 = (uint4*)d_ws;                 // 147,456 B

    prep_b2<<<36, 256, 0, stream>>>(mem, Bt2);
    convf<<<1024, 512, 0, stream>>>(x, Bt2, out);
}